// Round 1
// baseline (143.713 us; speedup 1.0000x reference)
//
#include <hip/hip_runtime.h>
#include <math.h>

#define HH 1024
#define WW 1024
#define RR 8192
#define EPSD 1e-10

// ws layout (bytes):
//   [0,         4194304)  rowpref: fp32 per-row prefix sums (1024*1024 f32)
//   [4194304,  12582912)  C: fp64 integral image (1024*1024 f64)
//   [12582912, 13107200)  bsum (64*1024 f64) column chunk sums (16-row chunks)
//   [13107200, 13139968)  iou (8192 f32)
//   [13139968, 13140008)  stats: 5 f64  {Su, Su2, Ss, Ss2, Sab}
//   [13140032, 13141056)  flags: 256 u32 (col-scan lookback, (chunk,cblk))
//   [13141056, 13141060)  ticket: 1 u32 (pair_prod last-block finalize)
#define OFF_C     4194304
#define OFF_BSUM  12582912
#define OFF_IOU   13107200
#define OFF_STAT  13139968
#define OFF_FLAG  13140032
#define OFF_TICK  13141056

typedef float v2f __attribute__((ext_vector_type(2)));

__device__ __forceinline__ float sigm(float a, float b) {
    // softmax over 2 channels, channel 1: 1/(1+exp(a-b)); fp32 fast path
    float z = (a - b) * 1.44269504088896f;          // log2(e)
    float e = __builtin_amdgcn_exp2f(z);            // v_exp_f32
    return __builtin_amdgcn_rcpf(1.0f + e);         // v_rcp_f32
}

// Kernel A: per-row prefix sum of sigmoid(seg1-seg0), fp32 out. One block per row.
// Block 0 also zero-inits stats accumulators, lookback flags, and the ticket
// (ws is poisoned between replays; stream order makes these visible to later kernels).
__global__ __launch_bounds__(256) void row_scan(const float* __restrict__ seg,
                                                float* __restrict__ rowpref,
                                                double* __restrict__ stats,
                                                unsigned* __restrict__ flags,
                                                unsigned* __restrict__ ticket) {
    if (blockIdx.x == 0) {
        if (threadIdx.x < 5) stats[threadIdx.x] = 0.0;
        flags[threadIdx.x] = 0u;               // 256 threads cover 256 flags
        if (threadIdx.x == 0) *ticket = 0u;
    }
    const int h = blockIdx.x;
    const int t = threadIdx.x;
    const float4* s0 = (const float4*)(seg + (size_t)h * WW);
    const float4* s1 = (const float4*)(seg + (size_t)(HH * WW) + (size_t)h * WW);
    float4 a = s0[t];
    float4 b = s1[t];
    float p0 = sigm(a.x, b.x);
    float p1 = p0 + sigm(a.y, b.y);
    float p2 = p1 + sigm(a.z, b.z);
    float p3 = p2 + sigm(a.w, b.w);

    // fp32 inclusive scan of per-thread totals across the block
    float tsum = p3;
    const int lane = t & 63, wid = t >> 6;
    #pragma unroll
    for (int off = 1; off < 64; off <<= 1) {
        float n = __shfl_up(tsum, off, 64);
        if (lane >= off) tsum += n;
    }
    __shared__ float wsum[4];
    if (lane == 63) wsum[wid] = tsum;
    __syncthreads();
    float woff = 0.0f;
    for (int k = 0; k < wid; ++k) woff += wsum[k];
    const float excl = woff + tsum - p3;

    float4 o;
    o.x = excl + p0;
    o.y = excl + p1;
    o.z = excl + p2;
    o.w = excl + p3;
    ((float4*)(rowpref + (size_t)h * WW))[t] = o;
}

// Kernel B (fused): per-(16-row chunk, column) partial sums kept in registers,
// publish chunk totals to bsum + flag, lookback over preceding chunks, then
// write the fp64 integral image C. grid (4, 64) = 256 blocks — all co-resident,
// and every predecessor (same c, smaller chunk) has a smaller flat block id,
// so forward progress is guaranteed even under partial residency.
__global__ __launch_bounds__(256) void col_scan_fused(const float* __restrict__ rowpref,
                                                      double* __restrict__ bsum,
                                                      double* __restrict__ C,
                                                      unsigned* __restrict__ flags) {
    const int c = blockIdx.x;            // 0..3  (column group of 256)
    const int chunk = blockIdx.y;        // 0..63 (16-row chunk)
    const int t = threadIdx.x;
    const int w = c * 256 + t;
    const int r0 = chunk * 16;

    double part[16];
    double acc = 0.0;
    #pragma unroll
    for (int r = 0; r < 16; ++r) {
        acc += (double)rowpref[(size_t)(r0 + r) * WW + w];
        part[r] = acc;
    }
    bsum[chunk * WW + w] = acc;          // publish chunk total (coalesced)
    __syncthreads();                     // all stores of this block issued & drained
    __threadfence();                     // device-visible (L2 writeback)
    if (t == 0)
        __hip_atomic_store(&flags[chunk * 4 + c], 1u,
                           __ATOMIC_RELEASE, __HIP_MEMORY_SCOPE_AGENT);

    // lookback: wait for all predecessor chunks in this column group
    if (t == 0) {
        for (int kp = 0; kp < chunk; ++kp)
            while (__hip_atomic_load(&flags[kp * 4 + c],
                                     __ATOMIC_RELAXED, __HIP_MEMORY_SCOPE_AGENT) == 0u) {}
    }
    __syncthreads();
    __threadfence();                     // acquire: invalidate before reading bsum

    double base = 0.0;
    #pragma unroll 4
    for (int kp = 0; kp < chunk; ++kp) base += bsum[kp * WW + w];

    #pragma unroll
    for (int r = 0; r < 16; ++r)
        C[(size_t)(r0 + r) * WW + w] = base + part[r];
}

// Kernel C: per-box iou + fp64 reductions of {Σu, Σu², Σs, Σs²}.
// 64 blocks × 128 threads: spreads the latency-bound gather over 64 CUs.
__global__ __launch_bounds__(128) void box_stats(const int* __restrict__ ssw,
                                                 const double* __restrict__ C,
                                                 const float* __restrict__ score,
                                                 float* __restrict__ iou,
                                                 double* __restrict__ stats) {
    const int r = blockIdx.x * 128 + threadIdx.x;
    const int* b = ssw + r * 5;
    const int x1 = b[1], y1 = b[2], x2 = b[3], y2 = b[4];
    double p22 = C[(size_t)(y2 - 1) * WW + (x2 - 1)];
    double p12 = (y1 > 0) ? C[(size_t)(y1 - 1) * WW + (x2 - 1)] : 0.0;
    double p21 = (x1 > 0) ? C[(size_t)(y2 - 1) * WW + (x1 - 1)] : 0.0;
    double p11 = (y1 > 0 && x1 > 0) ? C[(size_t)(y1 - 1) * WW + (x1 - 1)] : 0.0;
    double sums = p22 - p12 - p21 + p11;
    double area = (double)((y2 - y1) * (x2 - x1));
    double u = sums / area;
    iou[r] = (float)u;
    double s = (double)score[r];

    double v0 = u, v1 = u * u, v2 = s, v3 = s * s;
    #pragma unroll
    for (int off = 32; off; off >>= 1) {
        v0 += __shfl_down(v0, off, 64);
        v1 += __shfl_down(v1, off, 64);
        v2 += __shfl_down(v2, off, 64);
        v3 += __shfl_down(v3, off, 64);
    }
    if ((threadIdx.x & 63) == 0) {
        atomicAdd(&stats[0], v0);
        atomicAdd(&stats[1], v1);
        atomicAdd(&stats[2], v2);
        atomicAdd(&stats[3], v3);
    }
}

// Kernel D: S_ab = Σ_ij |du|·|ds|  (≈ Σ sqrt((du²+ε)(ds²+ε)), error < 1e-7 in loss).
// float2-packed inner loop (v_pk_add/mul_f32 + abs-modifier adds): ~2.5 inst/pair.
// Last block (ticket) folds in the finalize step.
#define KI 4
#define JT 128
__global__ __launch_bounds__(256) void pair_prod(const float* __restrict__ iou,
                                                 const float* __restrict__ score,
                                                 double* __restrict__ stats,
                                                 float* __restrict__ out,
                                                 unsigned* __restrict__ ticket) {
    __shared__ v2f ju[JT / 2];
    __shared__ v2f js[JT / 2];
    const int t = threadIdx.x;
    const int j0 = blockIdx.y * JT;
    if (t < JT / 2) ju[t] = ((const v2f*)(iou + j0))[t];
    else if (t < JT) js[t - JT / 2] = ((const v2f*)(score + j0))[t - JT / 2];

    const int i0 = blockIdx.x * (256 * KI) + t;
    v2f iuv[KI], isv[KI];
    #pragma unroll
    for (int k = 0; k < KI; ++k) {
        float u = iou[i0 + 256 * k];
        float s = score[i0 + 256 * k];
        iuv[k] = (v2f){u, u};
        isv[k] = (v2f){s, s};
    }
    __syncthreads();

    float ax[KI], ay[KI];
    #pragma unroll
    for (int k = 0; k < KI; ++k) { ax[k] = 0.0f; ay[k] = 0.0f; }
    #pragma unroll 4
    for (int j = 0; j < JT / 2; ++j) {
        const v2f uj = ju[j];
        const v2f sj = js[j];
        #pragma unroll
        for (int k = 0; k < KI; ++k) {
            v2f du = iuv[k] - uj;      // v_pk_add_f32 (neg)
            v2f ds = isv[k] - sj;      // v_pk_add_f32 (neg)
            v2f p  = du * ds;          // v_pk_mul_f32
            ax[k] += fabsf(p.x);       // v_add_f32 |src|
            ay[k] += fabsf(p.y);       // v_add_f32 |src|
        }
    }
    float afl = ((ax[0] + ay[0]) + (ax[1] + ay[1]))
              + ((ax[2] + ay[2]) + (ax[3] + ay[3]));
    double v = (double)afl;
    #pragma unroll
    for (int off = 32; off; off >>= 1) v += __shfl_down(v, off, 64);
    __shared__ double wred[4];
    const int lane = t & 63, wid = t >> 6;
    if (lane == 0) wred[wid] = v;
    __syncthreads();
    if (t == 0) {
        atomicAdd(&stats[4], wred[0] + wred[1] + wred[2] + wred[3]);
        __threadfence();                               // order stats-add before ticket
        unsigned tk = atomicAdd(ticket, 1u);
        if (tk == (unsigned)(gridDim.x * gridDim.y - 1)) {
            __threadfence();                           // acquire all stats
            double Su  = __hip_atomic_load(&stats[0], __ATOMIC_RELAXED, __HIP_MEMORY_SCOPE_AGENT);
            double Su2 = __hip_atomic_load(&stats[1], __ATOMIC_RELAXED, __HIP_MEMORY_SCOPE_AGENT);
            double Ss  = __hip_atomic_load(&stats[2], __ATOMIC_RELAXED, __HIP_MEMORY_SCOPE_AGENT);
            double Ss2 = __hip_atomic_load(&stats[3], __ATOMIC_RELAXED, __HIP_MEMORY_SCOPE_AGENT);
            double Sab = __hip_atomic_load(&stats[4], __ATOMIC_RELAXED, __HIP_MEMORY_SCOPE_AGENT);
            const double R = (double)RR;
            double lossR2 = 2.0 * R * Su2 - 2.0 * Su * Su
                          + 2.0 * R * Ss2 - 2.0 * Ss * Ss
                          + 2.0 * R * R * EPSD
                          - 2.0 * Sab;
            out[0] = (float)(lossR2 / (R * R));
        }
    }
}

extern "C" void kernel_launch(void* const* d_in, const int* in_sizes, int n_in,
                              void* d_out, int out_size, void* d_ws, size_t ws_size,
                              hipStream_t stream) {
    const int*   ssw   = (const int*)d_in[0];
    const float* seg   = (const float*)d_in[1];
    const float* score = (const float*)d_in[2];

    float*    rowpref = (float*)d_ws;
    double*   C       = (double*)((char*)d_ws + OFF_C);
    double*   bsum    = (double*)((char*)d_ws + OFF_BSUM);
    float*    iou     = (float*)((char*)d_ws + OFF_IOU);
    double*   stats   = (double*)((char*)d_ws + OFF_STAT);
    unsigned* flags   = (unsigned*)((char*)d_ws + OFF_FLAG);
    unsigned* ticket  = (unsigned*)((char*)d_ws + OFF_TICK);

    row_scan<<<HH, 256, 0, stream>>>(seg, rowpref, stats, flags, ticket);
    col_scan_fused<<<dim3(4, 64), 256, 0, stream>>>(rowpref, bsum, C, flags);
    box_stats<<<RR / 128, 128, 0, stream>>>(ssw, C, score, iou, stats);
    pair_prod<<<dim3(RR / (256 * KI), RR / JT), 256, 0, stream>>>(iou, score, stats, (float*)d_out, ticket);
}

// Round 2
// 109.267 us; speedup vs baseline: 1.3153x; 1.3153x over previous
//
#include <hip/hip_runtime.h>
#include <math.h>

#define HH 1024
#define WW 1024
#define RR 8192
#define EPSD 1e-10

// ws layout (bytes):
//   [0,         4194304)  rowpref: fp32 per-row prefix sums (1024*1024 f32)
//   [4194304,  12582912)  C: fp64 integral image (1024*1024 f64)
//   [12582912, 13107200)  bsum (64*1024 f64) column chunk sums (16-row chunks)
//   [13107200, 13139968)  iou (8192 f32)
//   [13139968, 13140008)  stats: 5 f64  {Su, Su2, Ss, Ss2, Sab}
//   [13140032, 13140036)  ticket: 1 u32 (pair_prod last-block finalize)
#define OFF_C     4194304
#define OFF_BSUM  12582912
#define OFF_IOU   13107200
#define OFF_STAT  13139968
#define OFF_TICK  13140032

typedef float v2f __attribute__((ext_vector_type(2)));

__device__ __forceinline__ float sigm(float a, float b) {
    // softmax over 2 channels, channel 1: 1/(1+exp(a-b)); fp32 fast path
    float z = (a - b) * 1.44269504088896f;          // log2(e)
    float e = __builtin_amdgcn_exp2f(z);            // v_exp_f32
    return __builtin_amdgcn_rcpf(1.0f + e);         // v_rcp_f32
}

// Kernel A: per-row prefix sum of sigmoid(seg1-seg0), fp32 out. One block per row.
// Block 0 also zero-inits the stats accumulators and the finalize ticket.
__global__ __launch_bounds__(256) void row_scan(const float* __restrict__ seg,
                                                float* __restrict__ rowpref,
                                                double* __restrict__ stats,
                                                unsigned* __restrict__ ticket) {
    if (blockIdx.x == 0 && threadIdx.x < 8) {
        if (threadIdx.x < 5) stats[threadIdx.x] = 0.0;
        if (threadIdx.x == 7) *ticket = 0u;
    }
    const int h = blockIdx.x;
    const int t = threadIdx.x;
    const float4* s0 = (const float4*)(seg + (size_t)h * WW);
    const float4* s1 = (const float4*)(seg + (size_t)(HH * WW) + (size_t)h * WW);
    float4 a = s0[t];
    float4 b = s1[t];
    float p0 = sigm(a.x, b.x);
    float p1 = p0 + sigm(a.y, b.y);
    float p2 = p1 + sigm(a.z, b.z);
    float p3 = p2 + sigm(a.w, b.w);

    // fp32 inclusive scan of per-thread totals across the block
    float tsum = p3;
    const int lane = t & 63, wid = t >> 6;
    #pragma unroll
    for (int off = 1; off < 64; off <<= 1) {
        float n = __shfl_up(tsum, off, 64);
        if (lane >= off) tsum += n;
    }
    __shared__ float wsum[4];
    if (lane == 63) wsum[wid] = tsum;
    __syncthreads();
    float woff = 0.0f;
    for (int k = 0; k < wid; ++k) woff += wsum[k];
    const float excl = woff + tsum - p3;

    float4 o;
    o.x = excl + p0;
    o.y = excl + p1;
    o.z = excl + p2;
    o.w = excl + p3;
    ((float4*)(rowpref + (size_t)h * WW))[t] = o;
}

// Kernel B: per-(16-row chunk, column) partial sums (fp64 acc of fp32). grid (4, 64).
// Simple two-pass structure: NO inter-block sync (round-1 lookback fusion cost 50 µs
// of cross-XCD coherence latency to save a 0.7 µs re-read — never again).
__global__ __launch_bounds__(256) void col_partial(const float* __restrict__ rowpref,
                                                   double* __restrict__ bsum) {
    const int w = blockIdx.x * 256 + threadIdx.x;
    const int chunk = blockIdx.y;
    const int r0 = chunk * 16;
    double acc = 0.0;
    #pragma unroll
    for (int r = r0; r < r0 + 16; ++r) acc += (double)rowpref[(size_t)r * WW + w];
    bsum[chunk * WW + w] = acc;
}

// Kernel C: column scan; writes the fp64 integral image C. grid (4, 64).
__global__ __launch_bounds__(256) void col_scan(const float* __restrict__ rowpref,
                                                const double* __restrict__ bsum,
                                                double* __restrict__ C) {
    const int w = blockIdx.x * 256 + threadIdx.x;
    const int chunk = blockIdx.y;
    double acc = 0.0;
    for (int k = 0; k < chunk; ++k) acc += bsum[k * WW + w];
    const int r0 = chunk * 16;
    #pragma unroll
    for (int r = r0; r < r0 + 16; ++r) {
        acc += (double)rowpref[(size_t)r * WW + w];
        C[(size_t)r * WW + w] = acc;
    }
}

// Kernel D: per-box iou + fp64 reductions of {Σu, Σu², Σs, Σs²}.
// 64 blocks × 128 threads: spreads the latency-bound gather over 64 CUs.
__global__ __launch_bounds__(128) void box_stats(const int* __restrict__ ssw,
                                                 const double* __restrict__ C,
                                                 const float* __restrict__ score,
                                                 float* __restrict__ iou,
                                                 double* __restrict__ stats) {
    const int r = blockIdx.x * 128 + threadIdx.x;
    const int* b = ssw + r * 5;
    const int x1 = b[1], y1 = b[2], x2 = b[3], y2 = b[4];
    double p22 = C[(size_t)(y2 - 1) * WW + (x2 - 1)];
    double p12 = (y1 > 0) ? C[(size_t)(y1 - 1) * WW + (x2 - 1)] : 0.0;
    double p21 = (x1 > 0) ? C[(size_t)(y2 - 1) * WW + (x1 - 1)] : 0.0;
    double p11 = (y1 > 0 && x1 > 0) ? C[(size_t)(y1 - 1) * WW + (x1 - 1)] : 0.0;
    double sums = p22 - p12 - p21 + p11;
    double area = (double)((y2 - y1) * (x2 - x1));
    double u = sums / area;
    iou[r] = (float)u;
    double s = (double)score[r];

    double v0 = u, v1 = u * u, v2 = s, v3 = s * s;
    #pragma unroll
    for (int off = 32; off; off >>= 1) {
        v0 += __shfl_down(v0, off, 64);
        v1 += __shfl_down(v1, off, 64);
        v2 += __shfl_down(v2, off, 64);
        v3 += __shfl_down(v3, off, 64);
    }
    if ((threadIdx.x & 63) == 0) {
        atomicAdd(&stats[0], v0);
        atomicAdd(&stats[1], v1);
        atomicAdd(&stats[2], v2);
        atomicAdd(&stats[3], v3);
    }
}

// Kernel E: S_ab = Σ_ij |du|·|ds|  (≈ Σ sqrt((du²+ε)(ds²+ε)), error < 1e-7 in loss).
// float2-packed inner loop (v_pk_add/mul_f32 + abs-modifier adds): ~2.5 inst/pair.
// Last block (ticket) folds in the finalize step — saves the 1-thread launch.
#define KI 4
#define JT 128
__global__ __launch_bounds__(256) void pair_prod(const float* __restrict__ iou,
                                                 const float* __restrict__ score,
                                                 double* __restrict__ stats,
                                                 float* __restrict__ out,
                                                 unsigned* __restrict__ ticket) {
    __shared__ v2f ju[JT / 2];
    __shared__ v2f js[JT / 2];
    const int t = threadIdx.x;
    const int j0 = blockIdx.y * JT;
    if (t < JT / 2) ju[t] = ((const v2f*)(iou + j0))[t];
    else if (t < JT) js[t - JT / 2] = ((const v2f*)(score + j0))[t - JT / 2];

    const int i0 = blockIdx.x * (256 * KI) + t;
    v2f iuv[KI], isv[KI];
    #pragma unroll
    for (int k = 0; k < KI; ++k) {
        float u = iou[i0 + 256 * k];
        float s = score[i0 + 256 * k];
        iuv[k] = (v2f){u, u};
        isv[k] = (v2f){s, s};
    }
    __syncthreads();

    float ax[KI], ay[KI];
    #pragma unroll
    for (int k = 0; k < KI; ++k) { ax[k] = 0.0f; ay[k] = 0.0f; }
    #pragma unroll 4
    for (int j = 0; j < JT / 2; ++j) {
        const v2f uj = ju[j];
        const v2f sj = js[j];
        #pragma unroll
        for (int k = 0; k < KI; ++k) {
            v2f du = iuv[k] - uj;      // v_pk_add_f32 (neg)
            v2f ds = isv[k] - sj;      // v_pk_add_f32 (neg)
            v2f p  = du * ds;          // v_pk_mul_f32
            ax[k] += fabsf(p.x);       // v_add_f32 |src|
            ay[k] += fabsf(p.y);       // v_add_f32 |src|
        }
    }
    float afl = ((ax[0] + ay[0]) + (ax[1] + ay[1]))
              + ((ax[2] + ay[2]) + (ax[3] + ay[3]));
    double v = (double)afl;
    #pragma unroll
    for (int off = 32; off; off >>= 1) v += __shfl_down(v, off, 64);
    __shared__ double wred[4];
    const int lane = t & 63, wid = t >> 6;
    if (lane == 0) wred[wid] = v;
    __syncthreads();
    if (t == 0) {
        atomicAdd(&stats[4], wred[0] + wred[1] + wred[2] + wred[3]);
        __threadfence();                               // order stats-add before ticket
        unsigned tk = atomicAdd(ticket, 1u);
        if (tk == (unsigned)(gridDim.x * gridDim.y - 1)) {
            __threadfence();                           // acquire all stats
            double Su  = __hip_atomic_load(&stats[0], __ATOMIC_RELAXED, __HIP_MEMORY_SCOPE_AGENT);
            double Su2 = __hip_atomic_load(&stats[1], __ATOMIC_RELAXED, __HIP_MEMORY_SCOPE_AGENT);
            double Ss  = __hip_atomic_load(&stats[2], __ATOMIC_RELAXED, __HIP_MEMORY_SCOPE_AGENT);
            double Ss2 = __hip_atomic_load(&stats[3], __ATOMIC_RELAXED, __HIP_MEMORY_SCOPE_AGENT);
            double Sab = __hip_atomic_load(&stats[4], __ATOMIC_RELAXED, __HIP_MEMORY_SCOPE_AGENT);
            const double R = (double)RR;
            double lossR2 = 2.0 * R * Su2 - 2.0 * Su * Su
                          + 2.0 * R * Ss2 - 2.0 * Ss * Ss
                          + 2.0 * R * R * EPSD
                          - 2.0 * Sab;
            out[0] = (float)(lossR2 / (R * R));
        }
    }
}

extern "C" void kernel_launch(void* const* d_in, const int* in_sizes, int n_in,
                              void* d_out, int out_size, void* d_ws, size_t ws_size,
                              hipStream_t stream) {
    const int*   ssw   = (const int*)d_in[0];
    const float* seg   = (const float*)d_in[1];
    const float* score = (const float*)d_in[2];

    float*    rowpref = (float*)d_ws;
    double*   C       = (double*)((char*)d_ws + OFF_C);
    double*   bsum    = (double*)((char*)d_ws + OFF_BSUM);
    float*    iou     = (float*)((char*)d_ws + OFF_IOU);
    double*   stats   = (double*)((char*)d_ws + OFF_STAT);
    unsigned* ticket  = (unsigned*)((char*)d_ws + OFF_TICK);

    row_scan<<<HH, 256, 0, stream>>>(seg, rowpref, stats, ticket);
    col_partial<<<dim3(4, 64), 256, 0, stream>>>(rowpref, bsum);
    col_scan<<<dim3(4, 64), 256, 0, stream>>>(rowpref, bsum, C);
    box_stats<<<RR / 128, 128, 0, stream>>>(ssw, C, score, iou, stats);
    pair_prod<<<dim3(RR / (256 * KI), RR / JT), 256, 0, stream>>>(iou, score, stats, (float*)d_out, ticket);
}